// Round 1
// baseline (344.725 us; speedup 1.0000x reference)
//
#include <hip/hip_runtime.h>

// Problem: total = l1 + 0.5*(1 - mean(ssim3d)),  volumes (4,1,128,128,128) f32
// SSIM window 11, zero-padded box sums, divide by 11^3 everywhere.

#define NB 4
#define ND 128
#define NH 128
#define NW 128
#define PLANE (NH * NW)            // 16384
#define VOL (ND * PLANE)           // 2,097,152
#define VOL4 (NB * VOL)            // 8,388,608
#define K1_BLOCKS (NB * ND * 8)    // 4096 (h tiled by 16)
#define K2_BLOCKS ((VOL4 / 256 / 32) * 4 * 32 / 32)  // see launch: 1024

__device__ __forceinline__ float fsel(bool c, float a, float b) { return c ? a : b; }

// ---------------- Kernel 1: fused W+H box sums of 5 fields + L1 partials ----
__global__ __launch_bounds__(256) void k_wh(const float* __restrict__ p,
                                            const float* __restrict__ t,
                                            float* __restrict__ S5,
                                            float* __restrict__ l1p)
{
    __shared__ float ws[5][26][128];   // W-summed fields, rows h0-5..h0+20
    __shared__ float red[256];

    const int bid   = blockIdx.x;
    const int htile = bid & 7;
    const int d     = (bid >> 3) & 127;
    const int b     = bid >> 10;
    const int h0    = htile * 16;
    const int tid   = threadIdx.x;

    float l1_local = 0.f;

    // Stage A: W-direction 11-tap sums (zero pad outside [0,128))
    for (int idx = tid; idx < 26 * 128; idx += 256) {
        const int r = idx >> 7;        // 0..25
        const int w = idx & 127;
        const int h = h0 - 5 + r;
        float sp = 0.f, st = 0.f, spp = 0.f, stt = 0.f, spt = 0.f;
        if (h >= 0 && h < NH) {
            const int base = ((b * ND + d) * NH + h) * NW;
#pragma unroll
            for (int dw = -5; dw <= 5; ++dw) {
                const int w2 = w + dw;
                if (w2 >= 0 && w2 < NW) {
                    const float pv = p[base + w2];
                    const float tv = t[base + w2];
                    sp += pv;  st += tv;
                    spp = fmaf(pv, pv, spp);
                    stt = fmaf(tv, tv, stt);
                    spt = fmaf(pv, tv, spt);
                    // center tap of an owned output row -> count |p-t| exactly once
                    if (dw == 0 && r >= 5 && r < 21)
                        l1_local += fabsf(pv - tv);
                }
            }
        }
        ws[0][r][w] = sp;  ws[1][r][w] = st;  ws[2][r][w] = spp;
        ws[3][r][w] = stt; ws[4][r][w] = spt;
    }
    __syncthreads();

    // Stage B: H-direction 11-tap sums, write 5 fields to global
    for (int idx = tid; idx < 16 * 128; idx += 256) {
        const int ho = idx >> 7;       // 0..15
        const int w  = idx & 127;
        float a0 = 0.f, a1 = 0.f, a2 = 0.f, a3 = 0.f, a4 = 0.f;
#pragma unroll
        for (int dr = 0; dr < 11; ++dr) {
            const int r = ho + dr;     // input h = h0 + ho + dr - 5  (pad handled in A)
            a0 += ws[0][r][w]; a1 += ws[1][r][w]; a2 += ws[2][r][w];
            a3 += ws[3][r][w]; a4 += ws[4][r][w];
        }
        const int o = ((b * ND + d) * NH + (h0 + ho)) * NW + w;
        S5[0 * VOL4 + o] = a0;
        S5[1 * VOL4 + o] = a1;
        S5[2 * VOL4 + o] = a2;
        S5[3 * VOL4 + o] = a3;
        S5[4 * VOL4 + o] = a4;
    }

    // block-reduce the L1 partial
    red[tid] = l1_local;
    __syncthreads();
    for (int s = 128; s > 0; s >>= 1) {
        if (tid < s) red[tid] += red[tid + s];
        __syncthreads();
    }
    if (tid == 0) l1p[bid] = red[0];
}

// ---------------- Kernel 2: D-direction sliding window + SSIM + reduce ------
__global__ __launch_bounds__(256) void k_d_ssim(const float* __restrict__ S5,
                                                float* __restrict__ ssimp)
{
    __shared__ float red[256];
    const float INV = 1.0f / 1331.0f;
    const float C1f = 1e-4f, C2f = 9e-4f;

    const int bid = blockIdx.x;      // 1024 blocks
    const int dc  = bid & 3;         // d chunk (32 deep)
    const int tid = threadIdx.x;
    const int lin = ((bid >> 2) << 8) + tid;   // 0..65535 -> (b,h,w)
    const int w = lin & 127;
    const int h = (lin >> 7) & 127;
    const int b = lin >> 14;
    const int d0 = dc * 32;
    const int base0 = b * VOL + h * NW + w;

    float rs0 = 0.f, rs1 = 0.f, rs2 = 0.f, rs3 = 0.f, rs4 = 0.f;
    // init window [d0-5, d0+5] ∩ [0,128)
    for (int dd = d0 - 5; dd <= d0 + 5; ++dd) {
        if (dd >= 0 && dd < ND) {
            const int a = base0 + dd * PLANE;
            rs0 += S5[0 * VOL4 + a];
            rs1 += S5[1 * VOL4 + a];
            rs2 += S5[2 * VOL4 + a];
            rs3 += S5[3 * VOL4 + a];
            rs4 += S5[4 * VOL4 + a];
        }
    }

    float acc = 0.f;
    for (int d = d0; d < d0 + 32; ++d) {
        const float mu_p  = rs0 * INV;
        const float mu_t  = rs1 * INV;
        const float mu_p2 = mu_p * mu_p;
        const float mu_t2 = mu_t * mu_t;
        const float mu_pt = mu_p * mu_t;
        const float sig_p  = rs2 * INV - mu_p2;
        const float sig_t  = rs3 * INV - mu_t2;
        const float sig_pt = rs4 * INV - mu_pt;
        const float num = (2.f * mu_pt + C1f) * (2.f * sig_pt + C2f);
        const float den = (mu_p2 + mu_t2 + C1f) * (sig_p + sig_t + C2f);
        acc += num / den;

        // slide window to d+1: add plane d+6, drop plane d-5
        const int da = d + 6, ds = d - 5;
        if (da < ND) {
            const int a = base0 + da * PLANE;
            rs0 += S5[0 * VOL4 + a];
            rs1 += S5[1 * VOL4 + a];
            rs2 += S5[2 * VOL4 + a];
            rs3 += S5[3 * VOL4 + a];
            rs4 += S5[4 * VOL4 + a];
        }
        if (ds >= 0) {
            const int a = base0 + ds * PLANE;
            rs0 -= S5[0 * VOL4 + a];
            rs1 -= S5[1 * VOL4 + a];
            rs2 -= S5[2 * VOL4 + a];
            rs3 -= S5[3 * VOL4 + a];
            rs4 -= S5[4 * VOL4 + a];
        }
    }

    red[tid] = acc;
    __syncthreads();
    for (int s = 128; s > 0; s >>= 1) {
        if (tid < s) red[tid] += red[tid + s];
        __syncthreads();
    }
    if (tid == 0) ssimp[bid] = red[0];
}

// ---------------- Kernel 3: final deterministic reduction -------------------
__global__ __launch_bounds__(256) void k_final(const float* __restrict__ l1p,
                                               const float* __restrict__ sp,
                                               float* __restrict__ out)
{
    __shared__ double r1[256];
    __shared__ double r2[256];
    const int tid = threadIdx.x;
    double s1 = 0.0, s2 = 0.0;
    for (int i = tid; i < K1_BLOCKS; i += 256) s1 += (double)l1p[i];
    for (int i = tid; i < 1024; i += 256)      s2 += (double)sp[i];
    r1[tid] = s1; r2[tid] = s2;
    __syncthreads();
    for (int s = 128; s > 0; s >>= 1) {
        if (tid < s) { r1[tid] += r1[tid + s]; r2[tid] += r2[tid + s]; }
        __syncthreads();
    }
    if (tid == 0) {
        const double N = (double)VOL4;
        const double l1        = r1[0] / N;
        const double ssim_mean = r2[0] / N;
        const double ssim_loss = 1.0 - ssim_mean;
        out[0] = (float)(l1 + 0.5 * ssim_loss);  // total
        out[1] = (float)l1;                      // l1_loss
        out[2] = (float)ssim_loss;               // ssim_loss
        out[3] = 0.f;                            // reg_loss
    }
}

extern "C" void kernel_launch(void* const* d_in, const int* in_sizes, int n_in,
                              void* d_out, int out_size, void* d_ws, size_t ws_size,
                              hipStream_t stream)
{
    const float* pred = (const float*)d_in[0];
    const float* targ = (const float*)d_in[1];
    float* out = (float*)d_out;

    float* S5    = (float*)d_ws;            // 5 * VOL4 floats = 167.8 MB
    float* l1p   = S5 + 5 * (size_t)VOL4;   // 4096 floats
    float* ssimp = l1p + K1_BLOCKS;         // 1024 floats

    k_wh<<<K1_BLOCKS, 256, 0, stream>>>(pred, targ, S5, l1p);
    k_d_ssim<<<1024, 256, 0, stream>>>(S5, ssimp);
    k_final<<<1, 256, 0, stream>>>(l1p, ssimp, out);
}

// Round 2
// 125.146 us; speedup vs baseline: 2.7546x; 2.7546x over previous
//
#include <hip/hip_runtime.h>

// total = l1 + 0.5*(1 - mean(ssim3d)), volumes (4,1,128,128,128) f32
// SSIM window 11, zero-padded box sums, /11^3.

#define NB 4
#define ND 128
#define NH 128
#define NW 128
#define PLANE (NH * NW)            // 16384
#define VOL (ND * PLANE)           // 2,097,152
#define VOL4 (NB * VOL)            // 8,388,608
#define K1_BLOCKS (NB * ND * 8)    // 4096 (h tiled by 16)

// ---------------- Kernel 1: fused W+H box sums of 5 fields + L1 partials ----
// Stage A: per-thread sliding 11-row H-sums (registers), coalesced row loads.
// Stage B: per-thread sliding 11-col W-sums from LDS, float4 stores.
__global__ __launch_bounds__(256) void k_wh(const float* __restrict__ p,
                                            const float* __restrict__ t,
                                            float* __restrict__ S5,
                                            float* __restrict__ l1p)
{
    __shared__ float hs[5][16][138];   // H-summed fields, w-padded by 5 each side
    __shared__ float red[256];

    const int bid   = blockIdx.x;
    const int htile = bid & 7;
    const int d     = (bid >> 3) & 127;
    const int b     = bid >> 10;
    const int h0    = htile * 16;
    const int tid   = threadIdx.x;

    // zero the w-halo columns of hs: cols 0..4 and 133..137
    for (int idx = tid; idx < 5 * 16 * 10; idx += 256) {
        const int f = idx / 160;
        const int rem = idx - f * 160;
        const int r = rem / 10;
        const int c10 = rem - r * 10;
        const int col = (c10 < 5) ? c10 : (128 + c10);
        hs[f][r][col] = 0.f;
    }

    // ---- Stage A: H-direction sliding sums ----
    const int w  = tid & 127;
    const int c  = tid >> 7;          // 0 or 1: owns output rows hbase..hbase+7
    const int hbase = h0 + c * 8;
    const int pbase = ((b * ND + d) * NH) * NW + w;

    float rp[11], rt[11];
    float s0 = 0.f, s1 = 0.f, s2 = 0.f, s3 = 0.f, s4 = 0.f;
    float l1_local = 0.f;

#pragma unroll
    for (int i = 0; i < 11; ++i) {
        const int h = hbase - 5 + i;
        float pv = 0.f, tv = 0.f;
        if (h >= 0 && h < NH) {
            pv = p[pbase + h * NW];
            tv = t[pbase + h * NW];
        }
        rp[i] = pv; rt[i] = tv;
        s0 += pv; s1 += tv;
        s2 = fmaf(pv, pv, s2);
        s3 = fmaf(tv, tv, s3);
        s4 = fmaf(pv, tv, s4);
        if (i >= 5) l1_local += fabsf(pv - tv);   // owned rows hbase..hbase+5
    }
    // output row 0 of this chunk
    {
        const int r = c * 8;
        hs[0][r][w + 5] = s0; hs[1][r][w + 5] = s1; hs[2][r][w + 5] = s2;
        hs[3][r][w + 5] = s3; hs[4][r][w + 5] = s4;
    }
#pragma unroll
    for (int j = 1; j < 8; ++j) {
        const int h = hbase + j + 5;         // incoming row
        float pv = 0.f, tv = 0.f;
        if (h < NH) {                        // h >= 0 always here
            pv = p[pbase + h * NW];
            tv = t[pbase + h * NW];
        }
        if (j <= 2) l1_local += fabsf(pv - tv);  // owned rows hbase+6, hbase+7
        const float op = rp[j - 1], ot = rt[j - 1];
        s0 += pv - op;
        s1 += tv - ot;
        s2 += fmaf(pv, pv, -(op * op));
        s3 += fmaf(tv, tv, -(ot * ot));
        s4 += fmaf(pv, tv, -(op * ot));
        rp[j - 1] = pv; rt[j - 1] = tv;
        const int r = c * 8 + j;
        hs[0][r][w + 5] = s0; hs[1][r][w + 5] = s1; hs[2][r][w + 5] = s2;
        hs[3][r][w + 5] = s3; hs[4][r][w + 5] = s4;
    }
    __syncthreads();

    // ---- Stage B: W-direction sliding sums from LDS, write 5 fields ----
    const int ho = tid >> 4;          // 0..15
    const int wc = tid & 15;          // 0..15, owns w in [8*wc, 8*wc+8)
    const int wbase = wc * 8;
    const int obase = ((b * ND + d) * NH + (h0 + ho)) * NW + wbase;

#pragma unroll
    for (int f = 0; f < 5; ++f) {
        float ring[11];
        float s = 0.f;
#pragma unroll
        for (int j = 0; j < 11; ++j) {
            ring[j] = hs[f][ho][wbase + j];
            s += ring[j];
        }
        float o[8];
        o[0] = s;
#pragma unroll
        for (int k = 1; k < 8; ++k) {
            const float nv = hs[f][ho][wbase + 10 + k];
            s += nv - ring[k - 1];
            o[k] = s;
        }
        float4 v0 = make_float4(o[0], o[1], o[2], o[3]);
        float4 v1 = make_float4(o[4], o[5], o[6], o[7]);
        *(float4*)&S5[(size_t)f * VOL4 + obase]     = v0;
        *(float4*)&S5[(size_t)f * VOL4 + obase + 4] = v1;
    }

    // block-reduce L1 partial
    red[tid] = l1_local;
    __syncthreads();
    for (int s = 128; s > 0; s >>= 1) {
        if (tid < s) red[tid] += red[tid + s];
        __syncthreads();
    }
    if (tid == 0) l1p[bid] = red[0];
}

// ---------------- Kernel 2: D-direction sliding window + SSIM + reduce ------
__global__ __launch_bounds__(256) void k_d_ssim(const float* __restrict__ S5,
                                                float* __restrict__ ssimp)
{
    __shared__ float red[256];
    const float INV = 1.0f / 1331.0f;
    const float C1f = 1e-4f, C2f = 9e-4f;

    const int bid = blockIdx.x;      // 1024 blocks
    const int dc  = bid & 3;         // d chunk (32 deep)
    const int tid = threadIdx.x;
    const int lin = ((bid >> 2) << 8) + tid;   // 0..65535 -> (b,h,w)
    const int w = lin & 127;
    const int h = (lin >> 7) & 127;
    const int b = lin >> 14;
    const int d0 = dc * 32;
    const int base0 = b * VOL + h * NW + w;

    float rs0 = 0.f, rs1 = 0.f, rs2 = 0.f, rs3 = 0.f, rs4 = 0.f;
    for (int dd = d0 - 5; dd <= d0 + 5; ++dd) {
        if (dd >= 0 && dd < ND) {
            const int a = base0 + dd * PLANE;
            rs0 += S5[0 * (size_t)VOL4 + a];
            rs1 += S5[1 * (size_t)VOL4 + a];
            rs2 += S5[2 * (size_t)VOL4 + a];
            rs3 += S5[3 * (size_t)VOL4 + a];
            rs4 += S5[4 * (size_t)VOL4 + a];
        }
    }

    float acc = 0.f;
    for (int d = d0; d < d0 + 32; ++d) {
        const float mu_p  = rs0 * INV;
        const float mu_t  = rs1 * INV;
        const float mu_p2 = mu_p * mu_p;
        const float mu_t2 = mu_t * mu_t;
        const float mu_pt = mu_p * mu_t;
        const float sig_p  = rs2 * INV - mu_p2;
        const float sig_t  = rs3 * INV - mu_t2;
        const float sig_pt = rs4 * INV - mu_pt;
        const float num = (2.f * mu_pt + C1f) * (2.f * sig_pt + C2f);
        const float den = (mu_p2 + mu_t2 + C1f) * (sig_p + sig_t + C2f);
        acc += num / den;

        const int da = d + 6, ds = d - 5;
        if (da < ND) {
            const int a = base0 + da * PLANE;
            rs0 += S5[0 * (size_t)VOL4 + a];
            rs1 += S5[1 * (size_t)VOL4 + a];
            rs2 += S5[2 * (size_t)VOL4 + a];
            rs3 += S5[3 * (size_t)VOL4 + a];
            rs4 += S5[4 * (size_t)VOL4 + a];
        }
        if (ds >= 0) {
            const int a = base0 + ds * PLANE;
            rs0 -= S5[0 * (size_t)VOL4 + a];
            rs1 -= S5[1 * (size_t)VOL4 + a];
            rs2 -= S5[2 * (size_t)VOL4 + a];
            rs3 -= S5[3 * (size_t)VOL4 + a];
            rs4 -= S5[4 * (size_t)VOL4 + a];
        }
    }

    red[tid] = acc;
    __syncthreads();
    for (int s = 128; s > 0; s >>= 1) {
        if (tid < s) red[tid] += red[tid + s];
        __syncthreads();
    }
    if (tid == 0) ssimp[bid] = red[0];
}

// ---------------- Kernel 3: final deterministic reduction -------------------
__global__ __launch_bounds__(256) void k_final(const float* __restrict__ l1p,
                                               const float* __restrict__ sp,
                                               float* __restrict__ out)
{
    __shared__ double r1[256];
    __shared__ double r2[256];
    const int tid = threadIdx.x;
    double s1 = 0.0, s2 = 0.0;
    for (int i = tid; i < K1_BLOCKS; i += 256) s1 += (double)l1p[i];
    for (int i = tid; i < 1024; i += 256)      s2 += (double)sp[i];
    r1[tid] = s1; r2[tid] = s2;
    __syncthreads();
    for (int s = 128; s > 0; s >>= 1) {
        if (tid < s) { r1[tid] += r1[tid + s]; r2[tid] += r2[tid + s]; }
        __syncthreads();
    }
    if (tid == 0) {
        const double N = (double)VOL4;
        const double l1        = r1[0] / N;
        const double ssim_mean = r2[0] / N;
        const double ssim_loss = 1.0 - ssim_mean;
        out[0] = (float)(l1 + 0.5 * ssim_loss);  // total
        out[1] = (float)l1;                      // l1_loss
        out[2] = (float)ssim_loss;               // ssim_loss
        out[3] = 0.f;                            // reg_loss
    }
}

extern "C" void kernel_launch(void* const* d_in, const int* in_sizes, int n_in,
                              void* d_out, int out_size, void* d_ws, size_t ws_size,
                              hipStream_t stream)
{
    const float* pred = (const float*)d_in[0];
    const float* targ = (const float*)d_in[1];
    float* out = (float*)d_out;

    float* S5    = (float*)d_ws;            // 5 * VOL4 floats = 167.8 MB
    float* l1p   = S5 + 5 * (size_t)VOL4;   // 4096 floats
    float* ssimp = l1p + K1_BLOCKS;         // 1024 floats

    k_wh<<<K1_BLOCKS, 256, 0, stream>>>(pred, targ, S5, l1p);
    k_d_ssim<<<1024, 256, 0, stream>>>(S5, ssimp);
    k_final<<<1, 256, 0, stream>>>(l1p, ssimp, out);
}

// Round 3
// 115.372 us; speedup vs baseline: 2.9879x; 1.0847x over previous
//
#include <hip/hip_runtime.h>
#include <hip/hip_fp16.h>

// total = l1 + 0.5*(1 - mean(ssim3d)), volumes (4,1,128,128,128) f32
// SSIM window 11, zero-padded box sums, /11^3.
// Intermediate WH-sums stored as f16 (values in [0,121], rel err 4.9e-4,
// unbiased -> final scalar error ~1e-4 vs 1.8e-2 threshold).

#define NB 4
#define ND 128
#define NH 128
#define NW 128
#define PLANE (NH * NW)            // 16384
#define VOL (ND * PLANE)           // 2,097,152
#define VOL4 (NB * VOL)            // 8,388,608
#define K1_BLOCKS (NB * ND * 8)    // 4096 (h tiled by 16)
#define K2_BLOCKS 512

typedef _Float16 half2v __attribute__((ext_vector_type(2)));

// XOR swizzle: kills stride-8-lane bank conflicts in stage B while keeping
// stage-A writes conflict-free. Injective; phys < 164 for c < 138.
__device__ __forceinline__ int swz(int c) { return c ^ ((c >> 5) << 2); }

// ---------------- Kernel 1: fused W+H box sums of 5 fields + L1 partials ----
__global__ __launch_bounds__(256) void k_wh(const float* __restrict__ p,
                                            const float* __restrict__ t,
                                            _Float16* __restrict__ S5,
                                            float* __restrict__ l1p)
{
    __shared__ float hs[5][16][164];   // H-summed fields, swizzled cols, 52.5 KB

    const int bid   = blockIdx.x;
    const int htile = bid & 7;
    const int d     = (bid >> 3) & 127;
    const int b     = bid >> 10;
    const int h0    = htile * 16;
    const int tid   = threadIdx.x;

    // zero the w-halo (logical cols 0..4 and 133..137)
    for (int idx = tid; idx < 5 * 16 * 10; idx += 256) {
        const int f = idx / 160;
        const int rem = idx - f * 160;
        const int r = rem / 10;
        const int c10 = rem - r * 10;
        const int col = (c10 < 5) ? c10 : (128 + c10);
        hs[f][r][swz(col)] = 0.f;
    }

    // ---- Stage A: H-direction sliding sums (registers) ----
    const int w  = tid & 127;
    const int c  = tid >> 7;          // 0/1: owns output rows hbase..hbase+7
    const int hbase = h0 + c * 8;
    const int pbase = ((b * ND + d) * NH) * NW + w;
    const int wcol = swz(w + 5);

    float rp[11], rt[11];
    float s0 = 0.f, s1 = 0.f, s2 = 0.f, s3 = 0.f, s4 = 0.f;
    float l1_local = 0.f;

#pragma unroll
    for (int i = 0; i < 11; ++i) {
        const int h = hbase - 5 + i;
        float pv = 0.f, tv = 0.f;
        if (h >= 0 && h < NH) {
            pv = p[pbase + h * NW];
            tv = t[pbase + h * NW];
        }
        rp[i] = pv; rt[i] = tv;
        s0 += pv; s1 += tv;
        s2 = fmaf(pv, pv, s2);
        s3 = fmaf(tv, tv, s3);
        s4 = fmaf(pv, tv, s4);
        if (i >= 5) l1_local += fabsf(pv - tv);   // owned rows hbase..hbase+5
    }
    {
        const int r = c * 8;
        hs[0][r][wcol] = s0; hs[1][r][wcol] = s1; hs[2][r][wcol] = s2;
        hs[3][r][wcol] = s3; hs[4][r][wcol] = s4;
    }
#pragma unroll
    for (int j = 1; j < 8; ++j) {
        const int h = hbase + j + 5;         // incoming row
        float pv = 0.f, tv = 0.f;
        if (h < NH) {
            pv = p[pbase + h * NW];
            tv = t[pbase + h * NW];
        }
        if (j <= 2) l1_local += fabsf(pv - tv);  // owned rows hbase+6, hbase+7
        const float op = rp[j - 1], ot = rt[j - 1];
        s0 += pv - op;
        s1 += tv - ot;
        s2 += fmaf(pv, pv, -(op * op));
        s3 += fmaf(tv, tv, -(ot * ot));
        s4 += fmaf(pv, tv, -(op * ot));
        rp[j - 1] = pv; rt[j - 1] = tv;
        const int r = c * 8 + j;
        hs[0][r][wcol] = s0; hs[1][r][wcol] = s1; hs[2][r][wcol] = s2;
        hs[3][r][wcol] = s3; hs[4][r][wcol] = s4;
    }
    __syncthreads();

    // ---- Stage B: W-direction sliding sums from LDS, f16 stores ----
    const int ho = tid >> 4;          // 0..15
    const int wc = tid & 15;          // owns w in [8*wc, 8*wc+8)
    const int wbase = wc * 8;
    const size_t obase = (size_t)((b * ND + d) * NH + (h0 + ho)) * NW + wbase;

#pragma unroll
    for (int f = 0; f < 5; ++f) {
        float ring[11];
        float s = 0.f;
#pragma unroll
        for (int j = 0; j < 11; ++j) {
            ring[j] = hs[f][ho][swz(wbase + j)];
            s += ring[j];
        }
        union { _Float16 h[8]; uint4 u; } o;
        o.h[0] = (_Float16)s;
#pragma unroll
        for (int k = 1; k < 8; ++k) {
            const float nv = hs[f][ho][swz(wbase + 10 + k)];
            s += nv - ring[k - 1];
            o.h[k] = (_Float16)s;
        }
        *(uint4*)&S5[(size_t)f * VOL4 + obase] = o.u;
    }

    // block-reduce L1 partial (alias reduction buffer onto hs)
    __syncthreads();
    float* red = &hs[0][0][0];
    red[tid] = l1_local;
    __syncthreads();
    for (int s = 128; s > 0; s >>= 1) {
        if (tid < s) red[tid] += red[tid + s];
        __syncthreads();
    }
    if (tid == 0) l1p[bid] = red[0];
}

// ---------------- Kernel 2: D-direction sliding window + SSIM + reduce ------
// Each thread owns a pair of w-columns (one f16x2 load serves 2 voxels).
__global__ __launch_bounds__(256) void k_d_ssim(const _Float16* __restrict__ S5,
                                                float* __restrict__ ssimp)
{
    __shared__ float red[256];
    const float INV = 1.0f / 1331.0f;
    const float C1f = 1e-4f, C2f = 9e-4f;

    const int bid = blockIdx.x;      // 512 blocks
    const int dc  = bid & 3;         // d chunk (32 deep)
    const int tid = threadIdx.x;
    const int idx = ((bid >> 2) << 8) + tid;   // 0..32767 -> (b,h,wpair)
    const int wp = idx & 63;
    const int h  = (idx >> 6) & 127;
    const int b  = idx >> 13;
    const int d0 = dc * 32;
    const int base0 = b * VOL + h * NW + wp * 2;

    float rsx[5] = {0.f, 0.f, 0.f, 0.f, 0.f};
    float rsy[5] = {0.f, 0.f, 0.f, 0.f, 0.f};

    for (int dd = d0 - 5; dd <= d0 + 5; ++dd) {
        if (dd >= 0 && dd < ND) {
            const size_t a = (size_t)base0 + (size_t)dd * PLANE;
#pragma unroll
            for (int f = 0; f < 5; ++f) {
                half2v v = *(const half2v*)&S5[(size_t)f * VOL4 + a];
                rsx[f] += (float)v[0];
                rsy[f] += (float)v[1];
            }
        }
    }

    float acc = 0.f;
    for (int d = d0; d < d0 + 32; ++d) {
        {
            const float mu_p  = rsx[0] * INV;
            const float mu_t  = rsx[1] * INV;
            const float mu_p2 = mu_p * mu_p;
            const float mu_t2 = mu_t * mu_t;
            const float mu_pt = mu_p * mu_t;
            const float sig_p  = rsx[2] * INV - mu_p2;
            const float sig_t  = rsx[3] * INV - mu_t2;
            const float sig_pt = rsx[4] * INV - mu_pt;
            const float num = (2.f * mu_pt + C1f) * (2.f * sig_pt + C2f);
            const float den = (mu_p2 + mu_t2 + C1f) * (sig_p + sig_t + C2f);
            acc += num / den;
        }
        {
            const float mu_p  = rsy[0] * INV;
            const float mu_t  = rsy[1] * INV;
            const float mu_p2 = mu_p * mu_p;
            const float mu_t2 = mu_t * mu_t;
            const float mu_pt = mu_p * mu_t;
            const float sig_p  = rsy[2] * INV - mu_p2;
            const float sig_t  = rsy[3] * INV - mu_t2;
            const float sig_pt = rsy[4] * INV - mu_pt;
            const float num = (2.f * mu_pt + C1f) * (2.f * sig_pt + C2f);
            const float den = (mu_p2 + mu_t2 + C1f) * (sig_p + sig_t + C2f);
            acc += num / den;
        }

        const int da = d + 6, ds = d - 5;
        if (da < ND) {
            const size_t a = (size_t)base0 + (size_t)da * PLANE;
#pragma unroll
            for (int f = 0; f < 5; ++f) {
                half2v v = *(const half2v*)&S5[(size_t)f * VOL4 + a];
                rsx[f] += (float)v[0];
                rsy[f] += (float)v[1];
            }
        }
        if (ds >= 0) {
            const size_t a = (size_t)base0 + (size_t)ds * PLANE;
#pragma unroll
            for (int f = 0; f < 5; ++f) {
                half2v v = *(const half2v*)&S5[(size_t)f * VOL4 + a];
                rsx[f] -= (float)v[0];
                rsy[f] -= (float)v[1];
            }
        }
    }

    red[tid] = acc;
    __syncthreads();
    for (int s = 128; s > 0; s >>= 1) {
        if (tid < s) red[tid] += red[tid + s];
        __syncthreads();
    }
    if (tid == 0) ssimp[bid] = red[0];
}

// ---------------- Kernel 3: final deterministic reduction -------------------
__global__ __launch_bounds__(256) void k_final(const float* __restrict__ l1p,
                                               const float* __restrict__ sp,
                                               float* __restrict__ out)
{
    __shared__ double r1[256];
    __shared__ double r2[256];
    const int tid = threadIdx.x;
    double s1 = 0.0, s2 = 0.0;
    for (int i = tid; i < K1_BLOCKS; i += 256) s1 += (double)l1p[i];
    for (int i = tid; i < K2_BLOCKS; i += 256) s2 += (double)sp[i];
    r1[tid] = s1; r2[tid] = s2;
    __syncthreads();
    for (int s = 128; s > 0; s >>= 1) {
        if (tid < s) { r1[tid] += r1[tid + s]; r2[tid] += r2[tid + s]; }
        __syncthreads();
    }
    if (tid == 0) {
        const double N = (double)VOL4;
        const double l1        = r1[0] / N;
        const double ssim_mean = r2[0] / N;
        const double ssim_loss = 1.0 - ssim_mean;
        out[0] = (float)(l1 + 0.5 * ssim_loss);  // total
        out[1] = (float)l1;                      // l1_loss
        out[2] = (float)ssim_loss;               // ssim_loss
        out[3] = 0.f;                            // reg_loss
    }
}

extern "C" void kernel_launch(void* const* d_in, const int* in_sizes, int n_in,
                              void* d_out, int out_size, void* d_ws, size_t ws_size,
                              hipStream_t stream)
{
    const float* pred = (const float*)d_in[0];
    const float* targ = (const float*)d_in[1];
    float* out = (float*)d_out;

    _Float16* S5 = (_Float16*)d_ws;                       // 5*VOL4*2B = 83.9 MB
    float* l1p   = (float*)((char*)d_ws + (size_t)5 * VOL4 * 2);
    float* ssimp = l1p + K1_BLOCKS;

    k_wh<<<K1_BLOCKS, 256, 0, stream>>>(pred, targ, S5, l1p);
    k_d_ssim<<<K2_BLOCKS, 256, 0, stream>>>(S5, ssimp);
    k_final<<<1, 256, 0, stream>>>(l1p, ssimp, out);
}

// Round 4
// 81.465 us; speedup vs baseline: 4.2316x; 1.4162x over previous
//
#include <hip/hip_runtime.h>
#include <hip/hip_fp16.h>

// total = l1 + 0.5*(1 - mean(ssim3d)), volumes (4,1,128,128,128) f32
// SSIM window 11, zero-padded box sums, /11^3.
// Intermediates (H-sums in LDS, WH-sums in workspace) stored as f16:
// values in [0,121], unbiased RNE rounding, final scalar err ~1e-4 << 1.8e-2.

#define NB 4
#define ND 128
#define NH 128
#define NW 128
#define PLANE (NH * NW)            // 16384
#define VOL (ND * PLANE)           // 2,097,152
#define VOL4 (NB * VOL)            // 8,388,608
#define K1_BLOCKS (NB * ND * 8)    // 4096 (h tiled by 16)
#define K2_BLOCKS 1024             // 8 d-chunks of 16 x 128 (b,h,wpair) groups

typedef _Float16 half2v __attribute__((ext_vector_type(2)));

// ---------------- Kernel 1: fused W+H box sums of 5 fields + L1 partials ----
// LDS layout: hs[f][r][c] f16, row stride 194 f16 = 97 words; 97 % 32 == 1.
// Stage B reads word (97*ho + 4*wc + j): bank = (ho + 4*wc + j) % 32 -> every
// bank exactly 2x across 64 lanes (2-way is free on CDNA4).
__global__ __launch_bounds__(256) void k_wh(const float* __restrict__ p,
                                            const float* __restrict__ t,
                                            _Float16* __restrict__ S5,
                                            float* __restrict__ l1p)
{
    __shared__ _Float16 hs[5][16][194];   // 31,040 B -> 5 blocks/CU

    const int bid   = blockIdx.x;
    const int htile = bid & 7;
    const int d     = (bid >> 3) & 127;
    const int b     = bid >> 10;
    const int h0    = htile * 16;
    const int tid   = threadIdx.x;

    // zero the w-halo (logical cols 0..4 and 133..137)
    for (int idx = tid; idx < 5 * 16 * 10; idx += 256) {
        const int f = idx / 160;
        const int rem = idx - f * 160;
        const int r = rem / 10;
        const int c10 = rem - r * 10;
        const int col = (c10 < 5) ? c10 : (128 + c10);
        hs[f][r][col] = (_Float16)0.f;
    }

    // ---- Stage A: H-direction sliding sums (registers) ----
    const int w  = tid & 127;
    const int c  = tid >> 7;          // 0/1: owns output rows hbase..hbase+7
    const int hbase = h0 + c * 8;
    const int pbase = ((b * ND + d) * NH) * NW + w;
    const int wcol = w + 5;

    float rp[11], rt[11];
    float s0 = 0.f, s1 = 0.f, s2 = 0.f, s3 = 0.f, s4 = 0.f;
    float l1_local = 0.f;

#pragma unroll
    for (int i = 0; i < 11; ++i) {
        const int h = hbase - 5 + i;
        float pv = 0.f, tv = 0.f;
        if (h >= 0 && h < NH) {
            pv = p[pbase + h * NW];
            tv = t[pbase + h * NW];
        }
        rp[i] = pv; rt[i] = tv;
        s0 += pv; s1 += tv;
        s2 = fmaf(pv, pv, s2);
        s3 = fmaf(tv, tv, s3);
        s4 = fmaf(pv, tv, s4);
        if (i >= 5) l1_local += fabsf(pv - tv);   // owned rows hbase..hbase+5
    }
    {
        const int r = c * 8;
        hs[0][r][wcol] = (_Float16)s0; hs[1][r][wcol] = (_Float16)s1;
        hs[2][r][wcol] = (_Float16)s2; hs[3][r][wcol] = (_Float16)s3;
        hs[4][r][wcol] = (_Float16)s4;
    }
#pragma unroll
    for (int j = 1; j < 8; ++j) {
        const int h = hbase + j + 5;         // incoming row
        float pv = 0.f, tv = 0.f;
        if (h < NH) {
            pv = p[pbase + h * NW];
            tv = t[pbase + h * NW];
        }
        if (j <= 2) l1_local += fabsf(pv - tv);  // owned rows hbase+6, hbase+7
        const float op = rp[j - 1], ot = rt[j - 1];
        s0 += pv - op;
        s1 += tv - ot;
        s2 += fmaf(pv, pv, -(op * op));
        s3 += fmaf(tv, tv, -(ot * ot));
        s4 += fmaf(pv, tv, -(op * ot));
        rp[j - 1] = pv; rt[j - 1] = tv;
        const int r = c * 8 + j;
        hs[0][r][wcol] = (_Float16)s0; hs[1][r][wcol] = (_Float16)s1;
        hs[2][r][wcol] = (_Float16)s2; hs[3][r][wcol] = (_Float16)s3;
        hs[4][r][wcol] = (_Float16)s4;
    }
    __syncthreads();

    // ---- Stage B: W-direction sliding sums from LDS pairs, f16 stores ----
    const int ho = tid >> 4;          // 0..15
    const int wc = tid & 15;          // owns w in [8*wc, 8*wc+8)
    const size_t obase = (size_t)((b * ND + d) * NH + (h0 + ho)) * NW + wc * 8;

#pragma unroll
    for (int f = 0; f < 5; ++f) {
        float arr[18];
#pragma unroll
        for (int j = 0; j < 9; ++j) {        // 9 x ds_read_b32, 2-way max
            const half2v hv = *(const half2v*)&hs[f][ho][8 * wc + 2 * j];
            arr[2 * j]     = (float)hv[0];
            arr[2 * j + 1] = (float)hv[1];
        }
        float s = 0.f;
#pragma unroll
        for (int j = 0; j < 11; ++j) s += arr[j];
        union { _Float16 h[8]; uint4 u; } o;
        o.h[0] = (_Float16)s;
#pragma unroll
        for (int k = 1; k < 8; ++k) {
            s += arr[10 + k] - arr[k - 1];
            o.h[k] = (_Float16)s;
        }
        *(uint4*)&S5[(size_t)f * VOL4 + obase] = o.u;
    }

    // block-reduce L1 partial (alias reduction buffer onto hs)
    __syncthreads();
    float* red = (float*)&hs[0][0][0];
    red[tid] = l1_local;
    __syncthreads();
    for (int s = 128; s > 0; s >>= 1) {
        if (tid < s) red[tid] += red[tid + s];
        __syncthreads();
    }
    if (tid == 0) l1p[bid] = red[0];
}

// ---------------- Kernel 2: D-direction sliding window + SSIM + reduce ------
// Each thread owns a pair of w-columns; d-chunks of 16 -> 1024 blocks.
__global__ __launch_bounds__(256) void k_d_ssim(const _Float16* __restrict__ S5,
                                                float* __restrict__ ssimp)
{
    __shared__ float red[256];
    const float INV = 1.0f / 1331.0f;
    const float C1f = 1e-4f, C2f = 9e-4f;

    const int bid = blockIdx.x;      // 1024 blocks
    const int dc  = bid & 7;         // d chunk (16 deep)
    const int tid = threadIdx.x;
    const int idx = ((bid >> 3) << 8) + tid;   // 0..32767 -> (b,h,wpair)
    const int wp = idx & 63;
    const int h  = (idx >> 6) & 127;
    const int b  = idx >> 13;
    const int d0 = dc * 16;
    const size_t base0 = (size_t)b * VOL + h * NW + wp * 2;

    const _Float16* F0 = S5 + 0 * (size_t)VOL4 + base0;
    const _Float16* F1 = S5 + 1 * (size_t)VOL4 + base0;
    const _Float16* F2 = S5 + 2 * (size_t)VOL4 + base0;
    const _Float16* F3 = S5 + 3 * (size_t)VOL4 + base0;
    const _Float16* F4 = S5 + 4 * (size_t)VOL4 + base0;

    float rsx[5] = {0.f, 0.f, 0.f, 0.f, 0.f};
    float rsy[5] = {0.f, 0.f, 0.f, 0.f, 0.f};

#define LOADF(F, dd) (*(const half2v*)&(F)[(size_t)(dd) * PLANE])
    for (int dd = d0 - 5; dd <= d0 + 5; ++dd) {
        if (dd >= 0 && dd < ND) {
            half2v v0 = LOADF(F0, dd), v1 = LOADF(F1, dd), v2 = LOADF(F2, dd),
                   v3 = LOADF(F3, dd), v4 = LOADF(F4, dd);
            rsx[0] += (float)v0[0]; rsy[0] += (float)v0[1];
            rsx[1] += (float)v1[0]; rsy[1] += (float)v1[1];
            rsx[2] += (float)v2[0]; rsy[2] += (float)v2[1];
            rsx[3] += (float)v3[0]; rsy[3] += (float)v3[1];
            rsx[4] += (float)v4[0]; rsy[4] += (float)v4[1];
        }
    }

    float acc = 0.f;
    for (int d = d0; d < d0 + 16; ++d) {
        {
            const float mu_p  = rsx[0] * INV;
            const float mu_t  = rsx[1] * INV;
            const float mu_p2 = mu_p * mu_p;
            const float mu_t2 = mu_t * mu_t;
            const float mu_pt = mu_p * mu_t;
            const float sig_p  = rsx[2] * INV - mu_p2;
            const float sig_t  = rsx[3] * INV - mu_t2;
            const float sig_pt = rsx[4] * INV - mu_pt;
            const float num = (2.f * mu_pt + C1f) * (2.f * sig_pt + C2f);
            const float den = (mu_p2 + mu_t2 + C1f) * (sig_p + sig_t + C2f);
            acc += num / den;
        }
        {
            const float mu_p  = rsy[0] * INV;
            const float mu_t  = rsy[1] * INV;
            const float mu_p2 = mu_p * mu_p;
            const float mu_t2 = mu_t * mu_t;
            const float mu_pt = mu_p * mu_t;
            const float sig_p  = rsy[2] * INV - mu_p2;
            const float sig_t  = rsy[3] * INV - mu_t2;
            const float sig_pt = rsy[4] * INV - mu_pt;
            const float num = (2.f * mu_pt + C1f) * (2.f * sig_pt + C2f);
            const float den = (mu_p2 + mu_t2 + C1f) * (sig_p + sig_t + C2f);
            acc += num / den;
        }

        const int da = d + 6, ds = d - 5;
        if (da < ND) {
            half2v v0 = LOADF(F0, da), v1 = LOADF(F1, da), v2 = LOADF(F2, da),
                   v3 = LOADF(F3, da), v4 = LOADF(F4, da);
            rsx[0] += (float)v0[0]; rsy[0] += (float)v0[1];
            rsx[1] += (float)v1[0]; rsy[1] += (float)v1[1];
            rsx[2] += (float)v2[0]; rsy[2] += (float)v2[1];
            rsx[3] += (float)v3[0]; rsy[3] += (float)v3[1];
            rsx[4] += (float)v4[0]; rsy[4] += (float)v4[1];
        }
        if (ds >= 0) {
            half2v v0 = LOADF(F0, ds), v1 = LOADF(F1, ds), v2 = LOADF(F2, ds),
                   v3 = LOADF(F3, ds), v4 = LOADF(F4, ds);
            rsx[0] -= (float)v0[0]; rsy[0] -= (float)v0[1];
            rsx[1] -= (float)v1[0]; rsy[1] -= (float)v1[1];
            rsx[2] -= (float)v2[0]; rsy[2] -= (float)v2[1];
            rsx[3] -= (float)v3[0]; rsy[3] -= (float)v3[1];
            rsx[4] -= (float)v4[0]; rsy[4] -= (float)v4[1];
        }
    }
#undef LOADF

    red[tid] = acc;
    __syncthreads();
    for (int s = 128; s > 0; s >>= 1) {
        if (tid < s) red[tid] += red[tid + s];
        __syncthreads();
    }
    if (tid == 0) ssimp[bid] = red[0];
}

// ---------------- Kernel 3: final deterministic reduction -------------------
__global__ __launch_bounds__(256) void k_final(const float* __restrict__ l1p,
                                               const float* __restrict__ sp,
                                               float* __restrict__ out)
{
    __shared__ double r1[256];
    __shared__ double r2[256];
    const int tid = threadIdx.x;
    double s1 = 0.0, s2 = 0.0;
    for (int i = tid; i < K1_BLOCKS; i += 256) s1 += (double)l1p[i];
    for (int i = tid; i < K2_BLOCKS; i += 256) s2 += (double)sp[i];
    r1[tid] = s1; r2[tid] = s2;
    __syncthreads();
    for (int s = 128; s > 0; s >>= 1) {
        if (tid < s) { r1[tid] += r1[tid + s]; r2[tid] += r2[tid + s]; }
        __syncthreads();
    }
    if (tid == 0) {
        const double N = (double)VOL4;
        const double l1        = r1[0] / N;
        const double ssim_mean = r2[0] / N;
        const double ssim_loss = 1.0 - ssim_mean;
        out[0] = (float)(l1 + 0.5 * ssim_loss);  // total
        out[1] = (float)l1;                      // l1_loss
        out[2] = (float)ssim_loss;               // ssim_loss
        out[3] = 0.f;                            // reg_loss
    }
}

extern "C" void kernel_launch(void* const* d_in, const int* in_sizes, int n_in,
                              void* d_out, int out_size, void* d_ws, size_t ws_size,
                              hipStream_t stream)
{
    const float* pred = (const float*)d_in[0];
    const float* targ = (const float*)d_in[1];
    float* out = (float*)d_out;

    _Float16* S5 = (_Float16*)d_ws;                       // 5*VOL4*2B = 83.9 MB
    float* l1p   = (float*)((char*)d_ws + (size_t)5 * VOL4 * 2);
    float* ssimp = l1p + K1_BLOCKS;

    k_wh<<<K1_BLOCKS, 256, 0, stream>>>(pred, targ, S5, l1p);
    k_d_ssim<<<K2_BLOCKS, 256, 0, stream>>>(S5, ssimp);
    k_final<<<1, 256, 0, stream>>>(l1p, ssimp, out);
}

// Round 5
// 70.436 us; speedup vs baseline: 4.8942x; 1.1566x over previous
//
#include <hip/hip_runtime.h>
#include <hip/hip_fp16.h>

// total = l1 + 0.5*(1 - mean(ssim3d)), volumes (4,1,128,128,128) f32
// SSIM window 11, zero-padded box sums, /11^3.
// Intermediates (H-sums in LDS, WH-sums in workspace) stored as f16:
// values in [0,121], unbiased RNE rounding, final scalar err ~1e-4 << 1.8e-2.

#define NB 4
#define ND 128
#define NH 128
#define NW 128
#define PLANE (NH * NW)            // 16384
#define VOL (ND * PLANE)           // 2,097,152
#define VOL4 (NB * VOL)            // 8,388,608
#define K1_BLOCKS (NB * ND * 8)    // 4096 (h tiled by 16)
#define K2_BLOCKS 1024             // 8 d-chunks of 16 x 128 (b,h) groups

typedef _Float16 half2v __attribute__((ext_vector_type(2)));

// ---------------- Kernel 1: fused W+H box sums of 5 fields + L1 partials ----
// LDS: hs[f][r][c] f16, row stride 194 f16 = 97 words; 97 % 32 == 1 ->
// stage-B reads hit every bank exactly 2x across 64 lanes (2-way is free).
// ONE barrier total: shfl-reduce the L1 partial after stage A, lane0 writes
// per-wave partial, barrier publishes hs + partials, stage B stores drain at
// endpgm (no trailing barrier -> no vmcnt(0) drain on the critical path).
__global__ __launch_bounds__(256) void k_wh(const float* __restrict__ p,
                                            const float* __restrict__ t,
                                            _Float16* __restrict__ S5,
                                            float* __restrict__ l1p)
{
    __shared__ _Float16 hs[5][16][194];   // 31,040 B
    __shared__ float red4[4];

    const int bid   = blockIdx.x;
    const int htile = bid & 7;
    const int d     = (bid >> 3) & 127;
    const int b     = bid >> 10;
    const int h0    = htile * 16;
    const int tid   = threadIdx.x;

    // zero the w-halo (logical cols 0..4 and 133..137)
    for (int idx = tid; idx < 5 * 16 * 10; idx += 256) {
        const int f = idx / 160;
        const int rem = idx - f * 160;
        const int r = rem / 10;
        const int c10 = rem - r * 10;
        const int col = (c10 < 5) ? c10 : (128 + c10);
        hs[f][r][col] = (_Float16)0.f;
    }

    // ---- Stage A: H-direction sliding sums (registers) ----
    const int w  = tid & 127;
    const int c  = tid >> 7;          // 0/1: owns output rows hbase..hbase+7
    const int hbase = h0 + c * 8;
    const int pbase = ((b * ND + d) * NH) * NW + w;
    const int wcol = w + 5;

    float rp[11], rt[11];
    float s0 = 0.f, s1 = 0.f, s2 = 0.f, s3 = 0.f, s4 = 0.f;
    float l1_local = 0.f;

#pragma unroll
    for (int i = 0; i < 11; ++i) {
        const int h = hbase - 5 + i;
        float pv = 0.f, tv = 0.f;
        if (h >= 0 && h < NH) {
            pv = p[pbase + h * NW];
            tv = t[pbase + h * NW];
        }
        rp[i] = pv; rt[i] = tv;
        s0 += pv; s1 += tv;
        s2 = fmaf(pv, pv, s2);
        s3 = fmaf(tv, tv, s3);
        s4 = fmaf(pv, tv, s4);
        if (i >= 5) l1_local += fabsf(pv - tv);   // owned rows hbase..hbase+5
    }
    {
        const int r = c * 8;
        hs[0][r][wcol] = (_Float16)s0; hs[1][r][wcol] = (_Float16)s1;
        hs[2][r][wcol] = (_Float16)s2; hs[3][r][wcol] = (_Float16)s3;
        hs[4][r][wcol] = (_Float16)s4;
    }
#pragma unroll
    for (int j = 1; j < 8; ++j) {
        const int h = hbase + j + 5;         // incoming row
        float pv = 0.f, tv = 0.f;
        if (h < NH) {
            pv = p[pbase + h * NW];
            tv = t[pbase + h * NW];
        }
        if (j <= 2) l1_local += fabsf(pv - tv);  // owned rows hbase+6, hbase+7
        const float op = rp[j - 1], ot = rt[j - 1];
        s0 += pv - op;
        s1 += tv - ot;
        s2 += fmaf(pv, pv, -(op * op));
        s3 += fmaf(tv, tv, -(ot * ot));
        s4 += fmaf(pv, tv, -(op * ot));
        rp[j - 1] = pv; rt[j - 1] = tv;
        const int r = c * 8 + j;
        hs[0][r][wcol] = (_Float16)s0; hs[1][r][wcol] = (_Float16)s1;
        hs[2][r][wcol] = (_Float16)s2; hs[3][r][wcol] = (_Float16)s3;
        hs[4][r][wcol] = (_Float16)s4;
    }

    // ---- L1 reduce: in-wave shuffle, one barrier ----
    {
        float v = l1_local;
#pragma unroll
        for (int off = 32; off > 0; off >>= 1) v += __shfl_down(v, off, 64);
        if ((tid & 63) == 0) red4[tid >> 6] = v;
    }
    __syncthreads();          // publishes hs (stage A + halo) and red4
    if (tid == 0) l1p[bid] = red4[0] + red4[1] + red4[2] + red4[3];

    // ---- Stage B: W-direction sliding sums from LDS pairs, f16 stores ----
    const int ho = tid >> 4;          // 0..15
    const int wc = tid & 15;          // owns w in [8*wc, 8*wc+8)
    const size_t obase = (size_t)((b * ND + d) * NH + (h0 + ho)) * NW + wc * 8;

#pragma unroll
    for (int f = 0; f < 5; ++f) {
        float arr[18];
#pragma unroll
        for (int j = 0; j < 9; ++j) {        // 9 x ds_read_b32, 2-way max
            const half2v hv = *(const half2v*)&hs[f][ho][8 * wc + 2 * j];
            arr[2 * j]     = (float)hv[0];
            arr[2 * j + 1] = (float)hv[1];
        }
        float s = 0.f;
#pragma unroll
        for (int j = 0; j < 11; ++j) s += arr[j];
        union { _Float16 h[8]; uint4 u; } o;
        o.h[0] = (_Float16)s;
#pragma unroll
        for (int k = 1; k < 8; ++k) {
            s += arr[10 + k] - arr[k - 1];
            o.h[k] = (_Float16)s;
        }
        *(uint4*)&S5[(size_t)f * VOL4 + obase] = o.u;
    }
    // no trailing barrier: stores drain at endpgm
}

// ---------------- Kernel 2: D-direction sliding window + SSIM + reduce ------
// Register ring buffer holds the 11-plane window (statically indexed via full
// unroll) -> each plane is LOADED ONCE (no subtract re-loads).
__global__ __launch_bounds__(256) void k_d_ssim(const _Float16* __restrict__ S5,
                                                float* __restrict__ ssimp)
{
    __shared__ float red4[4];
    const float INV = 1.0f / 1331.0f;
    const float C1f = 1e-4f, C2f = 9e-4f;

    const int bid = blockIdx.x;      // 1024 blocks
    const int dc  = bid & 7;         // d chunk (16 deep)
    const int tid = threadIdx.x;
    const int idx = ((bid >> 3) << 8) + tid;   // 0..32767 -> (b,h,wpair)
    const int wp = idx & 63;
    const int h  = (idx >> 6) & 127;
    const int b  = idx >> 13;
    const int d0 = dc * 16;
    const size_t base0 = (size_t)b * VOL + h * NW + wp * 2;

    const _Float16* F0 = S5 + 0 * (size_t)VOL4 + base0;
    const _Float16* F1 = S5 + 1 * (size_t)VOL4 + base0;
    const _Float16* F2 = S5 + 2 * (size_t)VOL4 + base0;
    const _Float16* F3 = S5 + 3 * (size_t)VOL4 + base0;
    const _Float16* F4 = S5 + 4 * (size_t)VOL4 + base0;

#define LOADF(F, dd) (*(const half2v*)&(F)[(size_t)(dd) * PLANE])

    half2v ring[5][11];               // window planes, slot = (plane-(d0-5))%11
    float rsx[5] = {0.f, 0.f, 0.f, 0.f, 0.f};
    float rsy[5] = {0.f, 0.f, 0.f, 0.f, 0.f};

    // init window: planes d0-5 .. d0+5 -> slots 0..10
#pragma unroll
    for (int o = -5; o <= 5; ++o) {
        const int dd = d0 + o;
        half2v v0, v1, v2, v3, v4;
        if (dd >= 0 && dd < ND) {
            v0 = LOADF(F0, dd); v1 = LOADF(F1, dd); v2 = LOADF(F2, dd);
            v3 = LOADF(F3, dd); v4 = LOADF(F4, dd);
        } else {
            v0 = v1 = v2 = v3 = v4 = (half2v)(_Float16)0.f;
        }
        ring[0][o + 5] = v0; ring[1][o + 5] = v1; ring[2][o + 5] = v2;
        ring[3][o + 5] = v3; ring[4][o + 5] = v4;
        rsx[0] += (float)v0[0]; rsy[0] += (float)v0[1];
        rsx[1] += (float)v1[0]; rsy[1] += (float)v1[1];
        rsx[2] += (float)v2[0]; rsy[2] += (float)v2[1];
        rsx[3] += (float)v3[0]; rsy[3] += (float)v3[1];
        rsx[4] += (float)v4[0]; rsy[4] += (float)v4[1];
    }

    float acc = 0.f;
#pragma unroll
    for (int s = 0; s < 16; ++s) {
        // SSIM at output plane d0+s (window currently [d0+s-5, d0+s+5])
        {
            const float mu_p  = rsx[0] * INV;
            const float mu_t  = rsx[1] * INV;
            const float mu_p2 = mu_p * mu_p;
            const float mu_t2 = mu_t * mu_t;
            const float mu_pt = mu_p * mu_t;
            const float sig_p  = rsx[2] * INV - mu_p2;
            const float sig_t  = rsx[3] * INV - mu_t2;
            const float sig_pt = rsx[4] * INV - mu_pt;
            const float num = (2.f * mu_pt + C1f) * (2.f * sig_pt + C2f);
            const float den = (mu_p2 + mu_t2 + C1f) * (sig_p + sig_t + C2f);
            acc = fmaf(num, __builtin_amdgcn_rcpf(den), acc);
        }
        {
            const float mu_p  = rsy[0] * INV;
            const float mu_t  = rsy[1] * INV;
            const float mu_p2 = mu_p * mu_p;
            const float mu_t2 = mu_t * mu_t;
            const float mu_pt = mu_p * mu_t;
            const float sig_p  = rsy[2] * INV - mu_p2;
            const float sig_t  = rsy[3] * INV - mu_t2;
            const float sig_pt = rsy[4] * INV - mu_pt;
            const float num = (2.f * mu_pt + C1f) * (2.f * sig_pt + C2f);
            const float den = (mu_p2 + mu_t2 + C1f) * (sig_p + sig_t + C2f);
            acc = fmaf(num, __builtin_amdgcn_rcpf(den), acc);
        }

        if (s < 15) {
            // slide: leaving plane d0+s-5 lives in slot s%11; incoming plane
            // d0+s+6 goes into the same slot.
            const int slot = s % 11;
            const int da = d0 + 6 + s;
            half2v n0, n1, n2, n3, n4;
            if (da < ND) {
                n0 = LOADF(F0, da); n1 = LOADF(F1, da); n2 = LOADF(F2, da);
                n3 = LOADF(F3, da); n4 = LOADF(F4, da);
            } else {
                n0 = n1 = n2 = n3 = n4 = (half2v)(_Float16)0.f;
            }
            rsx[0] += (float)n0[0] - (float)ring[0][slot][0];
            rsy[0] += (float)n0[1] - (float)ring[0][slot][1];
            rsx[1] += (float)n1[0] - (float)ring[1][slot][0];
            rsy[1] += (float)n1[1] - (float)ring[1][slot][1];
            rsx[2] += (float)n2[0] - (float)ring[2][slot][0];
            rsy[2] += (float)n2[1] - (float)ring[2][slot][1];
            rsx[3] += (float)n3[0] - (float)ring[3][slot][0];
            rsy[3] += (float)n3[1] - (float)ring[3][slot][1];
            rsx[4] += (float)n4[0] - (float)ring[4][slot][0];
            rsy[4] += (float)n4[1] - (float)ring[4][slot][1];
            ring[0][slot] = n0; ring[1][slot] = n1; ring[2][slot] = n2;
            ring[3][slot] = n3; ring[4][slot] = n4;
        }
    }
#undef LOADF

    // in-wave shuffle reduce, one barrier
    float v = acc;
#pragma unroll
    for (int off = 32; off > 0; off >>= 1) v += __shfl_down(v, off, 64);
    if ((tid & 63) == 0) red4[tid >> 6] = v;
    __syncthreads();
    if (tid == 0) ssimp[bid] = red4[0] + red4[1] + red4[2] + red4[3];
}

// ---------------- Kernel 3: final deterministic reduction -------------------
__global__ __launch_bounds__(256) void k_final(const float* __restrict__ l1p,
                                               const float* __restrict__ sp,
                                               float* __restrict__ out)
{
    __shared__ double r1[256];
    __shared__ double r2[256];
    const int tid = threadIdx.x;
    double s1 = 0.0, s2 = 0.0;
    for (int i = tid; i < K1_BLOCKS; i += 256) s1 += (double)l1p[i];
    for (int i = tid; i < K2_BLOCKS; i += 256) s2 += (double)sp[i];
    r1[tid] = s1; r2[tid] = s2;
    __syncthreads();
    for (int s = 128; s > 0; s >>= 1) {
        if (tid < s) { r1[tid] += r1[tid + s]; r2[tid] += r2[tid + s]; }
        __syncthreads();
    }
    if (tid == 0) {
        const double N = (double)VOL4;
        const double l1        = r1[0] / N;
        const double ssim_mean = r2[0] / N;
        const double ssim_loss = 1.0 - ssim_mean;
        out[0] = (float)(l1 + 0.5 * ssim_loss);  // total
        out[1] = (float)l1;                      // l1_loss
        out[2] = (float)ssim_loss;               // ssim_loss
        out[3] = 0.f;                            // reg_loss
    }
}

extern "C" void kernel_launch(void* const* d_in, const int* in_sizes, int n_in,
                              void* d_out, int out_size, void* d_ws, size_t ws_size,
                              hipStream_t stream)
{
    const float* pred = (const float*)d_in[0];
    const float* targ = (const float*)d_in[1];
    float* out = (float*)d_out;

    _Float16* S5 = (_Float16*)d_ws;                       // 5*VOL4*2B = 83.9 MB
    float* l1p   = (float*)((char*)d_ws + (size_t)5 * VOL4 * 2);
    float* ssimp = l1p + K1_BLOCKS;

    k_wh<<<K1_BLOCKS, 256, 0, stream>>>(pred, targ, S5, l1p);
    k_d_ssim<<<K2_BLOCKS, 256, 0, stream>>>(S5, ssimp);
    k_final<<<1, 256, 0, stream>>>(l1p, ssimp, out);
}